// Round 2
// baseline (391.181 us; speedup 1.0000x reference)
//
#include <hip/hip_runtime.h>

// LSTM B=4096 T=512 IN=14 H=28 OUT=2, fp32 in/out.
// Wave-autonomous formulation: the entire recurrence lives inside one wave.
// NO __syncthreads in the main loop, NO LDS in the main loop.
//   - A operand = weights (rows = gate-units via permuted map mu(s,r)), B = data
//     (cols = batches), D[unit][batch]. 8 tiles (gate g x unit-half s).
//   - mu(s,r) = 8*(r>>2) + 4s + (r&3) makes lane (q,m) hold ALL FOUR gates of
//     units 8q+2*(m>>2)+{0,1}, batch m&3, at static (tile, reg) indices after a
//     24-cndmask select. c-state stays in registers per lane.
//   - h_t -> bf16 pair (v_cvt_pk_bf16_f32) -> next step's B-frag gathered with
//     4 ds_bpermute (src lane = 16q + 4w + (m&3)); k=28..31 pad hits zero
//     weights so garbage lanes are harmless (preacts there are exactly 0).
//   - x streamed via depth-2 register pipeline (8B-aligned float2 loads);
//     x-MFMAs for step t+1 issued during step t (accx = bias + W_ih*x).
// 4 batches/wave -> 1024 waves = 1 wave/SIMD device-wide. Blocks of 256 carry
// 4 independent waves; one barrier at the very end for the tiny epilogue.

#define T_STEPS 512
#define BATCH   4096
#define IN_F    14
#define HID     28
#define OUT_N   2

typedef __attribute__((ext_vector_type(8))) short  short8;
typedef __attribute__((ext_vector_type(4))) float  float4v;
typedef __attribute__((ext_vector_type(4))) int    int4v;
typedef __attribute__((ext_vector_type(2))) float  float2v;

#define L1 1.4426950408889634f
#define L2 2.8853900817779268f

__device__ __forceinline__ unsigned short f2bf(float f) {
    union { float f; unsigned int u; } v; v.f = f;
    unsigned int r = (v.u + 0x7FFFu + ((v.u >> 16) & 1u)) >> 16;  // RNE
    return (unsigned short)r;
}

__device__ __forceinline__ int cvtpk_bf16(float lo, float hi) {
    int r;
    asm("v_cvt_pk_bf16_f32 %0, %1, %2" : "=v"(r) : "v"(lo), "v"(hi));
    return r;
}

__global__ __launch_bounds__(256, 1)
void lstm_wave(const float* __restrict__ x,
               const float* __restrict__ W_ih,
               const float* __restrict__ W_hh,
               const float* __restrict__ b_ih,
               const float* __restrict__ b_hh,
               const float* __restrict__ W_out,
               const float* __restrict__ b_out,
               float* __restrict__ out) {
    __shared__ float hfin[4][4][HID];   // [wave][b][u], epilogue only

    const int tid  = threadIdx.x;
    const int wid  = tid >> 6;
    const int l    = tid & 63;
    const int q    = l >> 4;       // k-octet / unit-row group
    const int m    = l & 15;       // C column
    const int p    = m >> 2;       // unit-pair selector within octet
    const int b3   = m & 3;        // batch within wave
    const int wave = blockIdx.x * 4 + wid;
    const int bbase = wave * 4;

    const bool pm1 = (p & 1) != 0;
    const bool pm2 = (p & 2) != 0;

    // ---- A-frag weights (bf16) + bias as C-init ----
    // A-frag: lane holds A row r = m, k = 8q+j.  Row r of tile (g,s) is weight
    // row g*28 + mu(s,r), mu(s,r) = 8*(r>>2)+4s+(r&3).
    short8  Ah[8], Ax[8];
    float4v bias8[8];
    #pragma unroll
    for (int g = 0; g < 4; ++g) {
        #pragma unroll
        for (int s = 0; s < 2; ++s) {
            const int ts = g * 2 + s;
            const int mu = 8 * p + 4 * s + b3;       // mu(s, r=m)
            const bool vr = (mu < HID);
            const int wrow = g * HID + (vr ? mu : 0);
            short8 vh, vx;
            #pragma unroll
            for (int j = 0; j < 8; ++j) {
                const int k = 8 * q + j;
                float wh = (vr && k < HID)  ? W_hh[wrow * HID + k] : 0.0f;
                float wx = (vr && k < IN_F) ? W_ih[wrow * IN_F + k] : 0.0f;
                vh[j] = (short)f2bf(wh);
                vx[j] = (short)f2bf(wx);
            }
            Ah[ts] = vh;
            Ax[ts] = vx;
            // C rows r_c = 4q+j  ->  unit mu_c = 8q+4s+j
            float4v bv;
            #pragma unroll
            for (int j = 0; j < 4; ++j) {
                const int muc = 8 * q + 4 * s + j;
                bv[j] = (muc < HID) ? (b_ih[g * HID + muc] + b_hh[g * HID + muc]) : 0.0f;
            }
            bias8[ts] = bv;
        }
    }

    // bpermute byte indices: word w comes from lane 16q + 4w + b3
    int bpidx[4];
    #pragma unroll
    for (int w = 0; w < 4; ++w) bpidx[w] = (q * 16 + 4 * w + b3) * 4;

    // ---- x pipeline: B-frag col = batch b3, k-feats 8q+e (q>=2 all zero) ----
    const float* xp = x + (long)(bbase + b3) * T_STEPS * IN_F;

    float2v rawA[4], rawB[4];
    auto loadraw = [&](int t, float2v (&r)[4]) {
        #pragma unroll
        for (int w = 0; w < 4; ++w) { r[w].x = 0.0f; r[w].y = 0.0f; }
        const float* pt = xp + (long)t * IN_F + 8 * q;   // 8B-aligned
        if (q == 0) {
            r[0] = *(const float2v*)(pt);
            r[1] = *(const float2v*)(pt + 2);
            r[2] = *(const float2v*)(pt + 4);
            r[3] = *(const float2v*)(pt + 6);
        } else if (q == 1) {
            r[0] = *(const float2v*)(pt);        // f8,9
            r[1] = *(const float2v*)(pt + 2);    // f10,11
            r[2] = *(const float2v*)(pt + 4);    // f12,13 ; word3 stays 0
        }
    };
    auto packx = [&](const float2v (&r)[4]) {
        int4v v;
        #pragma unroll
        for (int w = 0; w < 4; ++w) v[w] = cvtpk_bf16(r[w].x, r[w].y);
        return v;
    };

    // prologue: xw[0] -> accx init; xw[1] staged; raws for t=2,3 in flight
    loadraw(0, rawA);
    int4v xw0 = packx(rawA);
    loadraw(1, rawA);
    int4v xwB = packx(rawA);
    loadraw(2, rawA);
    loadraw(3, rawB);

    float4v accx[8];
    {
        short8 bx = __builtin_bit_cast(short8, xw0);
        #pragma unroll
        for (int ts = 0; ts < 8; ++ts)
            accx[ts] = __builtin_amdgcn_mfma_f32_16x16x32_bf16(Ax[ts], bx, bias8[ts], 0, 0, 0);
    }

    int   hword = 0;
    float c0 = 0.0f, c1 = 0.0f;
    float h0f = 0.0f, h1f = 0.0f;

    auto gate = [&](const float (&pr)[4], float& c, float& hf) {
        float ei = __builtin_amdgcn_exp2f(pr[0] * (-L1));
        float ef = __builtin_amdgcn_exp2f(pr[1] * (-L1));
        float eg = __builtin_amdgcn_exp2f(pr[2] * (-L2));
        float eo = __builtin_amdgcn_exp2f(pr[3] * (-L1));
        float av = 1.0f + ei, bv = 1.0f + ef, dv = 1.0f + eg, vv = 1.0f + eo;
        float pd  = av * dv;
        float pqv = pd * bv;
        float rv  = __builtin_amdgcn_rcpf(pqv);
        float sfv = pd * rv;                       // sigma(f)
        float igv = (1.0f - eg) * bv * rv;         // sigma(i)*tanh(g)
        c = fmaf(sfv, c, igv);
        float ec = __builtin_amdgcn_exp2f(c * (-L2));
        float wv = 1.0f + ec;
        float r2 = __builtin_amdgcn_rcpf(vv * wv);
        hf = (1.0f - ec) * r2;                     // sigma(o)*tanh(c)
    };

    auto STEP = [&](int4v xwn) {
        // gather h B-frag (4 bpermutes); first step hword==0 -> h0 = 0
        int4v bhv;
        #pragma unroll
        for (int w = 0; w < 4; ++w)
            bhv[w] = __builtin_amdgcn_ds_bpermute(bpidx[w], hword);
        short8 Bh = __builtin_bit_cast(short8, bhv);
        // h part on top of (bias + x*W_ih) computed last step
        float4v acch[8];
        #pragma unroll
        for (int ts = 0; ts < 8; ++ts)
            acch[ts] = __builtin_amdgcn_mfma_f32_16x16x32_bf16(Ah[ts], Bh, accx[ts], 0, 0, 0);
        // static-index select of this lane's 2 elements x 4 gates
        float pr0[4], pr1[4];
        #pragma unroll
        for (int g = 0; g < 4; ++g) {
            float4v A0 = acch[g * 2 + 0];
            float4v A1 = acch[g * 2 + 1];
            float t1 = pm1 ? A0[2] : A0[0];
            float t2 = pm1 ? A1[2] : A1[0];
            pr0[g] = pm2 ? t2 : t1;
            float u1 = pm1 ? A0[3] : A0[1];
            float u2 = pm1 ? A1[3] : A1[1];
            pr1[g] = pm2 ? u2 : u1;
        }
        // next step's x part (independent of h) -- overlaps with gate math
        short8 Bx = __builtin_bit_cast(short8, xwn);
        #pragma unroll
        for (int ts = 0; ts < 8; ++ts)
            accx[ts] = __builtin_amdgcn_mfma_f32_16x16x32_bf16(Ax[ts], Bx, bias8[ts], 0, 0, 0);
        gate(pr0, c0, h0f);
        gate(pr1, c1, h1f);
        hword = cvtpk_bf16(h0f, h1f);   // lo = unit 8q+2p, hi = +1
    };

    for (int it = 0; it < T_STEPS / 2; ++it) {
        int4v xa = packx(rawA);                         // xw[2it+2]
        int ta = 2 * it + 4; if (ta > T_STEPS - 1) ta = T_STEPS - 1;
        loadraw(ta, rawA);
        STEP(xwB);                                      // step 2it   (uses xw[2it+1])
        int4v xb = packx(rawB);                         // xw[2it+3]
        int tb = 2 * it + 5; if (tb > T_STEPS - 1) tb = T_STEPS - 1;
        loadraw(tb, rawB);
        STEP(xa);                                       // step 2it+1 (uses xw[2it+2])
        xwB = xb;
    }

    // ---- epilogue: out[b][o] = h_T[b] . W_out[o] + b_out[o] ----
    const int u0 = 8 * q + 2 * p;
    if (u0 < HID) {
        hfin[wid][b3][u0]     = h0f;
        hfin[wid][b3][u0 + 1] = h1f;
    }
    __syncthreads();
    if (tid < 32) {
        const int w2 = tid >> 3, i = tid & 7, bb = i >> 1, o = i & 1;
        float s = b_out[o];
        #pragma unroll
        for (int u = 0; u < HID; ++u)
            s = fmaf(hfin[w2][bb][u], W_out[o * HID + u], s);
        out[((blockIdx.x * 4 + w2) * 4 + bb) * OUT_N + o] = s;
    }
}

extern "C" void kernel_launch(void* const* d_in, const int* in_sizes, int n_in,
                              void* d_out, int out_size, void* d_ws, size_t ws_size,
                              hipStream_t stream) {
    const float* x     = (const float*)d_in[0];
    const float* W_ih  = (const float*)d_in[1];
    const float* W_hh  = (const float*)d_in[2];
    const float* b_ih  = (const float*)d_in[3];
    const float* b_hh  = (const float*)d_in[4];
    const float* W_out = (const float*)d_in[5];
    const float* b_out = (const float*)d_in[6];
    float* out = (float*)d_out;

    lstm_wave<<<BATCH / 16, 256, 0, stream>>>(
        x, W_ih, W_hh, b_ih, b_hh, W_out, b_out, out);
}

// Round 3
// 285.352 us; speedup vs baseline: 1.3709x; 1.3709x over previous
//
#include <hip/hip_runtime.h>

// LSTM B=4096 T=512 IN=14 H=28 OUT=2, fp32 in/out.
// Fused-gate cooperative kernel: wave w owns units [8w, 8w+8) for ALL FOUR
// gates, so the gate nonlinearity reads MFMA accumulators directly — no
// preact LDS exchange, no select, ONE barrier per step (h double-buffered).
//   A operand = weights: tile t (t=0,1) has 16 rows = (gate r&3, unit
//     8w + 2*(r>>2) + t). B operand = data: 16 cols = 16 batches.
//   Lane (q,m): C regs j = gate j preact of unit 8w+2q+t, batch m (static!).
//   Per step per wave: 2 ds_read_b128 (h, x) + 4 MFMA (x-part w/ bias init,
//   then h-part) + 2 merged-rcp gate chains + cvt_pk + 1 ds_write_b32.
//   h_a is double-buffered: read h_a[rb], write h_a[rb^1], one __syncthreads.
// Wave 3 covers units 24..27 only (lanes q>=2 idle in gate phase; their
// B-frag k=16..31 operands are still live, so they run the MFMAs).
// x staged per 16-step chunk into LDS (double-buffered), next chunk's global
// loads held in 14 VGPRs across the chunk (champion's latency-hiding trick).
// MB=16 batches/block, grid 256 -> 1 block/CU, 16 batches/CU.

#define T_STEPS 512
#define BATCH   4096
#define IN_F    14
#define HID     28
#define OUT_N   2
#define MB      16                 // batch per block
#define TC      16                 // timesteps per x chunk
#define NCHUNK  (T_STEPS / TC)     // 32
#define HPITCH  40                 // shorts per B-row (80 B, 16B-aligned, 2-way banks)
#define XREGS   ((MB * TC * IN_F) / 256)   // 14 fp32 per thread per chunk

typedef __attribute__((ext_vector_type(8))) short  short8;
typedef __attribute__((ext_vector_type(4))) float  float4v;

#define L1 1.4426950408889634f
#define L2 2.8853900817779268f

__device__ __forceinline__ unsigned short f2bf(float f) {
    union { float f; unsigned int u; } v; v.f = f;
    unsigned int r = (v.u + 0x7FFFu + ((v.u >> 16) & 1u)) >> 16;  // RNE
    return (unsigned short)r;
}

__device__ __forceinline__ int cvtpk_bf16(float lo, float hi) {
    int r;
    asm("v_cvt_pk_bf16_f32 %0, %1, %2" : "=v"(r) : "v"(lo), "v"(hi));
    return r;
}

__device__ __forceinline__ void gate4(const float4v pr, float& c, float& hf) {
    // pr[0]=i, pr[1]=f, pr[2]=g, pr[3]=o raw preacts
    float ei = __builtin_amdgcn_exp2f(pr[0] * (-L1));
    float ef = __builtin_amdgcn_exp2f(pr[1] * (-L1));
    float eg = __builtin_amdgcn_exp2f(pr[2] * (-L2));
    float eo = __builtin_amdgcn_exp2f(pr[3] * (-L1));
    float av = 1.0f + ei, bv = 1.0f + ef, dv = 1.0f + eg, vv = 1.0f + eo;
    float pd  = av * dv;
    float pqv = pd * bv;
    float rv  = __builtin_amdgcn_rcpf(pqv);
    float sfv = pd * rv;                       // sigma(f)
    float igv = (1.0f - eg) * bv * rv;         // sigma(i)*tanh(g)
    c = fmaf(sfv, c, igv);
    float ec = __builtin_amdgcn_exp2f(c * (-L2));
    float wv = 1.0f + ec;
    float r2 = __builtin_amdgcn_rcpf(vv * wv);
    hf = (1.0f - ec) * r2;                     // sigma(o)*tanh(c)
}

__global__ __launch_bounds__(256, 1)
void lstm_fuse(const float* __restrict__ x,
               const float* __restrict__ W_ih,
               const float* __restrict__ W_hh,
               const float* __restrict__ b_ih,
               const float* __restrict__ b_hh,
               const float* __restrict__ W_out,
               const float* __restrict__ b_out,
               float* __restrict__ out) {
    __shared__ __align__(16) short h_a[2][MB][HPITCH];         // bf16 h (units 0..27; 28..39 = 0)
    __shared__ __align__(16) short x_a[2][TC][MB][HPITCH];     // bf16 x (feats 0..13; 14..39 = 0)
    __shared__ float hfin[MB][HID];                            // f32 h for epilogue

    const int tid = threadIdx.x;
    const int w   = tid >> 6;        // wave: units [8w, 8w+8)
    const int l   = tid & 63;
    const int q   = l >> 4;
    const int m   = l & 15;          // batch within block (B cols)
    const int b0  = blockIdx.x * MB;

    // ---- A-frag weights (bf16) + bias as C-init ----
    // A-frag row = m: gate = m&3, unit_local = 2*(m>>2)+t; k = 8q+j.
    short8  Ah[2], Ax[2];
    float4v bias[2];
    #pragma unroll
    for (int t = 0; t < 2; ++t) {
        const int ul = 2 * (m >> 2) + t;
        const int ug = 8 * w + ul;
        const bool vr = (ug < HID);
        const int wrow = (m & 3) * HID + (vr ? ug : 0);
        short8 vh, vx;
        #pragma unroll
        for (int j = 0; j < 8; ++j) {
            const int k = 8 * q + j;
            float wh = (vr && k < HID)  ? W_hh[wrow * HID + k]  : 0.0f;
            float wx = (vr && k < IN_F) ? W_ih[wrow * IN_F + k] : 0.0f;
            vh[j] = (short)f2bf(wh);
            vx[j] = (short)f2bf(wx);
        }
        Ah[t] = vh;
        Ax[t] = vx;
        // C regs j = gate j of unit 8w+2q+t, batch m
        const int u = 8 * w + 2 * q + t;
        float4v bv;
        #pragma unroll
        for (int j = 0; j < 4; ++j)
            bv[j] = (u < HID) ? (b_ih[j * HID + u] + b_hh[j * HID + u]) : 0.0f;
        bias[t] = bv;
    }

    // ---- zero LDS (h0 = 0; pads stay 0 forever) ----
    for (int u = tid; u < 2 * MB * HPITCH; u += 256) ((short*)h_a)[u] = 0;
    for (int u = tid; u < 2 * TC * MB * HPITCH; u += 256) ((short*)x_a)[u] = 0;

    // ---- prefetch chunk 0 into registers ----
    const float* xbase = x + (long)b0 * T_STEPS * IN_F;
    float xr[XREGS];
    #pragma unroll
    for (int k = 0; k < XREGS; ++k) {
        const int u  = tid + 256 * k;
        const int bb = u / (TC * IN_F);
        const int r  = u - bb * (TC * IN_F);
        xr[k] = xbase[(long)bb * T_STEPS * IN_F + r];
    }
    __syncthreads();   // zero-init visible

    const int  ug0 = 8 * w + 2 * q;      // even; pairs (ug0, ug0+1)
    const bool vld = (ug0 < HID);        // wave 3, q>=2 -> false
    float c0 = 0.0f, c1 = 0.0f, h0f = 0.0f, h1f = 0.0f;
    int rb = 0;

    for (int ch = 0; ch < NCHUNK; ++ch) {
        const int buf = ch & 1;
        // convert held registers -> bf16 B-layout for this chunk
        #pragma unroll
        for (int k = 0; k < XREGS; ++k) {
            const int u  = tid + 256 * k;
            const int bb = u / (TC * IN_F);
            const int r  = u - bb * (TC * IN_F);
            const int t  = r / IN_F;
            const int f  = r - t * IN_F;
            x_a[buf][t][bb][f] = (short)f2bf(xr[k]);
        }
        // issue next chunk's global loads (consumed TC steps later)
        if (ch + 1 < NCHUNK) {
            #pragma unroll
            for (int k = 0; k < XREGS; ++k) {
                const int u  = tid + 256 * k;
                const int bb = u / (TC * IN_F);
                const int r  = u - bb * (TC * IN_F);
                xr[k] = xbase[(long)bb * T_STEPS * IN_F + (ch + 1) * TC * IN_F + r];
            }
        }
        __syncthreads();   // x_a[buf] visible

        for (int tt = 0; tt < TC; ++tt) {
            short8 bh = *(const short8*)&h_a[rb][m][8 * q];
            short8 bx = *(const short8*)&x_a[buf][tt][m][8 * q];
            // x part (bias init) first — issues while bh is in flight
            float4v a0 = __builtin_amdgcn_mfma_f32_16x16x32_bf16(Ax[0], bx, bias[0], 0, 0, 0);
            float4v a1 = __builtin_amdgcn_mfma_f32_16x16x32_bf16(Ax[1], bx, bias[1], 0, 0, 0);
            a0 = __builtin_amdgcn_mfma_f32_16x16x32_bf16(Ah[0], bh, a0, 0, 0, 0);
            a1 = __builtin_amdgcn_mfma_f32_16x16x32_bf16(Ah[1], bh, a1, 0, 0, 0);
            // lane (q,m): a_t[j] = gate-j preact of unit 8w+2q+t, batch m
            if (vld) {
                gate4(a0, c0, h0f);
                gate4(a1, c1, h1f);
                *(int*)&h_a[rb ^ 1][m][ug0] = cvtpk_bf16(h0f, h1f);
            }
            rb ^= 1;
            __syncthreads();   // h_{t+1} visible; safe to overwrite other buffer next step
        }
    }

    // ---- epilogue: out[b][o] = h_T[b] . W_out[o] + b_out[o] ----
    if (vld) {
        hfin[m][ug0]     = h0f;
        hfin[m][ug0 + 1] = h1f;
    }
    __syncthreads();
    if (tid < MB * OUT_N) {
        const int o  = tid & 1;
        const int bb = tid >> 1;
        float s = b_out[o];
        #pragma unroll
        for (int u = 0; u < HID; ++u)
            s = fmaf(hfin[bb][u], W_out[o * HID + u], s);
        out[(b0 + bb) * OUT_N + o] = s;
    }
}

extern "C" void kernel_launch(void* const* d_in, const int* in_sizes, int n_in,
                              void* d_out, int out_size, void* d_ws, size_t ws_size,
                              hipStream_t stream) {
    const float* x     = (const float*)d_in[0];
    const float* W_ih  = (const float*)d_in[1];
    const float* W_hh  = (const float*)d_in[2];
    const float* b_ih  = (const float*)d_in[3];
    const float* b_hh  = (const float*)d_in[4];
    const float* W_out = (const float*)d_in[5];
    const float* b_out = (const float*)d_in[6];
    float* out = (float*)d_out;

    lstm_fuse<<<BATCH / MB, 256, 0, stream>>>(
        x, W_ih, W_hh, b_ih, b_hh, W_out, b_out, out);
}

// Round 4
// 273.935 us; speedup vs baseline: 1.4280x; 1.0417x over previous
//
#include <hip/hip_runtime.h>

// LSTM B=4096 T=512 IN=14 H=28 OUT=2, fp32 in/out.
// 8-wave (512thr) fused-gate kernel, grid 256 -> 1 block/CU, 16 batches/CU,
// 2 waves/SIMD so co-resident waves hide each other's ds_read/barrier stalls.
// Waves 0..6 each own FOUR units (4w..4w+3) for ALL FOUR gates:
//   A operand = weights, 16 rows = (gate r&3, unit 4w + (r>>2));
//   B operand = data, 16 cols = 16 batches.
//   Lane (q,m): C reg j = gate-j preact of unit 4w+q, batch m (static) ->
//   ONE gate4 chain per lane, ONE h-MFMA per wave per step.
// x-projection off critical path: accx_{t+1} = bias + W_ih*x_{t+1} computed
// by an independent MFMA during step t (ping-pong named register).
// Step chain: read bh -> 1 MFMA (C=accx) -> gate4 -> ds_write_b16 h -> barrier.
// h double-buffered (read rb, write rb^1), ONE barrier per step.
// Wave 7 only helps stage x and syncs. x staged per 16-step chunk (double-
// buffered LDS), next chunk's global loads held in 7 VGPRs across the chunk.

#define T_STEPS 512
#define BATCH   4096
#define IN_F    14
#define HID     28
#define OUT_N   2
#define MB      16                 // batch per block
#define TC      16                 // timesteps per x chunk
#define NCHUNK  (T_STEPS / TC)     // 32
#define HPITCH  40                 // shorts per B-row (80 B, 16B-aligned, 2-way banks)
#define NTHR    512
#define XREGS   ((MB * TC * IN_F) / NTHR)   // 7 fp32 per thread per chunk

typedef __attribute__((ext_vector_type(8))) short  short8;
typedef __attribute__((ext_vector_type(4))) float  float4v;

#define L1 1.4426950408889634f
#define L2 2.8853900817779268f

__device__ __forceinline__ unsigned short f2bf(float f) {
    union { float f; unsigned int u; } v; v.f = f;
    unsigned int r = (v.u + 0x7FFFu + ((v.u >> 16) & 1u)) >> 16;  // RNE
    return (unsigned short)r;
}

__device__ __forceinline__ void gate4(const float4v pr, float& c, float& hf) {
    // pr[0]=i, pr[1]=f, pr[2]=g, pr[3]=o raw preacts
    float ei = __builtin_amdgcn_exp2f(pr[0] * (-L1));
    float ef = __builtin_amdgcn_exp2f(pr[1] * (-L1));
    float eg = __builtin_amdgcn_exp2f(pr[2] * (-L2));
    float eo = __builtin_amdgcn_exp2f(pr[3] * (-L1));
    float av = 1.0f + ei, bv = 1.0f + ef, dv = 1.0f + eg, vv = 1.0f + eo;
    float pd  = av * dv;
    float pqv = pd * bv;
    float rv  = __builtin_amdgcn_rcpf(pqv);
    float sfv = pd * rv;                       // sigma(f)
    float igv = (1.0f - eg) * bv * rv;         // sigma(i)*tanh(g)
    c = fmaf(sfv, c, igv);
    float ec = __builtin_amdgcn_exp2f(c * (-L2));
    float wv = 1.0f + ec;
    float r2 = __builtin_amdgcn_rcpf(vv * wv);
    hf = (1.0f - ec) * r2;                     // sigma(o)*tanh(c)
}

__global__ __launch_bounds__(512, 1)
void lstm_f8(const float* __restrict__ x,
             const float* __restrict__ W_ih,
             const float* __restrict__ W_hh,
             const float* __restrict__ b_ih,
             const float* __restrict__ b_hh,
             const float* __restrict__ W_out,
             const float* __restrict__ b_out,
             float* __restrict__ out) {
    __shared__ __align__(16) short h_a[2][MB][HPITCH];         // bf16 h (units 0..27; 28..39 = 0)
    __shared__ __align__(16) short x_a[2][TC][MB][HPITCH];     // bf16 x (feats 0..13; 14..39 = 0)
    __shared__ float hfin[MB][HID];                            // f32 h for epilogue

    const int tid = threadIdx.x;
    const int w   = tid >> 6;        // wave; 0..6 own units [4w, 4w+4)
    const int l   = tid & 63;
    const int q   = l >> 4;
    const int m   = l & 15;          // batch within block (B cols)
    const int b0  = blockIdx.x * MB;
    const bool act = (w < 7);
    const int u   = 4 * w + q;       // unit this lane owns (act only)

    // ---- A-frag weights (bf16) + bias as C-init ----
    // A-frag row = m: gate = m&3, unit = 4w + (m>>2); k = 8q+j.
    short8  Ah = {0,0,0,0,0,0,0,0}, Ax = {0,0,0,0,0,0,0,0};
    float4v bias = {0.0f, 0.0f, 0.0f, 0.0f};
    if (act) {
        const int unit = 4 * w + (m >> 2);               // 0..27, always valid
        const int wrow = (m & 3) * HID + unit;
        #pragma unroll
        for (int j = 0; j < 8; ++j) {
            const int k = 8 * q + j;
            float wh = (k < HID)  ? W_hh[wrow * HID + k]  : 0.0f;
            float wx = (k < IN_F) ? W_ih[wrow * IN_F + k] : 0.0f;
            Ah[j] = (short)f2bf(wh);
            Ax[j] = (short)f2bf(wx);
        }
        // C reg j = gate j of unit u, batch m
        #pragma unroll
        for (int j = 0; j < 4; ++j)
            bias[j] = b_ih[j * HID + u] + b_hh[j * HID + u];
    }

    // ---- zero LDS (h0 = 0; pads stay 0 forever) ----
    for (int k = tid; k < 2 * MB * HPITCH; k += NTHR) ((short*)h_a)[k] = 0;
    for (int k = tid; k < 2 * TC * MB * HPITCH; k += NTHR) ((short*)x_a)[k] = 0;

    // ---- prefetch chunk 0 into registers ----
    const float* xbase = x + (long)b0 * T_STEPS * IN_F;
    float xr[XREGS];
    #pragma unroll
    for (int k = 0; k < XREGS; ++k) {
        const int u2 = tid + NTHR * k;
        const int bb = u2 / (TC * IN_F);
        const int r  = u2 - bb * (TC * IN_F);
        xr[k] = xbase[(long)bb * T_STEPS * IN_F + r];
    }
    __syncthreads();   // zero-init visible

    float c = 0.0f, hf = 0.0f;
    int rb = 0;
    float4v accx = bias;

    for (int ch = 0; ch < NCHUNK; ++ch) {
        const int buf = ch & 1;
        // convert held registers -> bf16 B-layout for this chunk
        #pragma unroll
        for (int k = 0; k < XREGS; ++k) {
            const int u2 = tid + NTHR * k;
            const int bb = u2 / (TC * IN_F);
            const int r  = u2 - bb * (TC * IN_F);
            const int t  = r / IN_F;
            const int f  = r - t * IN_F;
            x_a[buf][t][bb][f] = (short)f2bf(xr[k]);
        }
        // issue next chunk's global loads (consumed TC steps later)
        if (ch + 1 < NCHUNK) {
            #pragma unroll
            for (int k = 0; k < XREGS; ++k) {
                const int u2 = tid + NTHR * k;
                const int bb = u2 / (TC * IN_F);
                const int r  = u2 - bb * (TC * IN_F);
                xr[k] = xbase[(long)bb * T_STEPS * IN_F + (ch + 1) * TC * IN_F + r];
            }
        }
        __syncthreads();   // x_a[buf] visible

        // accx for step 0 of this chunk (once per 16 steps on critical path)
        if (act) {
            short8 bx0 = *(const short8*)&x_a[buf][0][m][8 * q];
            accx = __builtin_amdgcn_mfma_f32_16x16x32_bf16(Ax, bx0, bias, 0, 0, 0);
        }

        for (int tt = 0; tt < TC; ++tt) {
            if (act) {
                short8 bh = *(const short8*)&h_a[rb][m][8 * q];
                float4v acc = __builtin_amdgcn_mfma_f32_16x16x32_bf16(Ah, bh, accx, 0, 0, 0);
                // next step's x part — independent, overlaps with gate math
                if (tt + 1 < TC) {
                    short8 bxn = *(const short8*)&x_a[buf][tt + 1][m][8 * q];
                    accx = __builtin_amdgcn_mfma_f32_16x16x32_bf16(Ax, bxn, bias, 0, 0, 0);
                }
                // lane (q,m): acc[j] = gate-j preact of unit u, batch m
                gate4(acc, c, hf);
                ((short*)&h_a[rb ^ 1][m][0])[u] = (short)f2bf(hf);
            }
            rb ^= 1;
            __syncthreads();   // h_{t+1} visible; other buffer free next step
        }
    }

    // ---- epilogue: out[b][o] = h_T[b] . W_out[o] + b_out[o] ----
    if (act) hfin[m][u] = hf;
    __syncthreads();
    if (tid < MB * OUT_N) {
        const int o  = tid & 1;
        const int bb = tid >> 1;
        float s = b_out[o];
        #pragma unroll
        for (int k = 0; k < HID; ++k)
            s = fmaf(hfin[bb][k], W_out[o * HID + k], s);
        out[(b0 + bb) * OUT_N + o] = s;
    }
}

extern "C" void kernel_launch(void* const* d_in, const int* in_sizes, int n_in,
                              void* d_out, int out_size, void* d_ws, size_t ws_size,
                              hipStream_t stream) {
    const float* x     = (const float*)d_in[0];
    const float* W_ih  = (const float*)d_in[1];
    const float* W_hh  = (const float*)d_in[2];
    const float* b_ih  = (const float*)d_in[3];
    const float* b_hh  = (const float*)d_in[4];
    const float* W_out = (const float*)d_in[5];
    const float* b_out = (const float*)d_in[6];
    float* out = (float*)d_out;

    lstm_f8<<<BATCH / MB, NTHR, 0, stream>>>(
        x, W_ih, W_hh, b_ih, b_hh, W_out, b_out, out);
}